// Round 1
// 428.294 us; speedup vs baseline: 1.0266x; 1.0266x over previous
//
#include <hip/hip_runtime.h>

using u16 = unsigned short;
using u32 = unsigned int;

typedef __attribute__((ext_vector_type(4))) float f32x4;
typedef __attribute__((ext_vector_type(8))) short frag8;   // 8 x bf16 (4 VGPRs)

#define HIDDEN 2048
#define SEQ    2048
#define NHEADS 16
#define HDIM   128

__device__ __forceinline__ float bf2f(u16 u) {
  union { u32 i; float f; } c; c.i = ((u32)u) << 16; return c.f;
}
__device__ __forceinline__ u16 f2bf(float f) {   // RNE
  union { float f; u32 i; } c; c.f = f;
  u32 u = c.i + 0x7fffu + ((c.i >> 16) & 1u);
  return (u16)(u >> 16);
}

// ---------------------------------------------------------------------------
// Fused f32 -> bf16 convert for X + 4 weight matrices, ONE dispatch.
// ---------------------------------------------------------------------------
__global__ void cvt_all(const float* __restrict__ X,
                        const float* __restrict__ W0, const float* __restrict__ W1,
                        const float* __restrict__ W2, const float* __restrict__ W3,
                        u16* __restrict__ dX,
                        u16* __restrict__ dW0, u16* __restrict__ dW1,
                        u16* __restrict__ dW2, u16* __restrict__ dW3)
{
  const int bx = blockIdx.x;
  const float* s; u16* d; int g;
  if (bx < 4096) { s = X; d = dX; g = bx * 256 + threadIdx.x; }
  else {
    const int t = bx - 4096;
    const int w = t >> 11;               // 0..3
    s = (w == 0) ? W0 : (w == 1) ? W1 : (w == 2) ? W2 : W3;
    d = (w == 0) ? dW0 : (w == 1) ? dW1 : (w == 2) ? dW2 : dW3;
    g = (t & 2047) * 256 + threadIdx.x;
  }
  const float* p = s + (size_t)g * 8;
  f32x4 x0 = *(const f32x4*)p, x1 = *(const f32x4*)(p + 4);
  frag8 o;
#pragma unroll
  for (int e = 0; e < 4; e++) { o[e] = (short)f2bf(x0[e]); o[e+4] = (short)f2bf(x1[e]); }
  *(frag8*)(d + (size_t)g * 8) = o;
}

// ---------------------------------------------------------------------------
// OLD 128x128 fused NT GEMM (kept for out-proj and the slow path).
// ---------------------------------------------------------------------------
template<int W_BF16, int NW, int VT, int C_F32>
__global__ __launch_bounds__(256, 4)
void gemm_fused(const u16* __restrict__ A,
                const void* __restrict__ W0, const void* __restrict__ W1,
                const void* __restrict__ W2,
                const float* __restrict__ bias0, const float* __restrict__ bias1,
                const float* __restrict__ bias2,
                void* __restrict__ C0, void* __restrict__ C1, void* __restrict__ C2)
{
  __shared__ __align__(16) u16 smem[8192];     // As [0,4096), Bs [4096,8192)
  u16* As = smem;
  u16* Bs = smem + 4096;

  const int tid  = threadIdx.x;
  const int lane = tid & 63;
  const int wv   = tid >> 6;
  const int quad = lane >> 4;
  const int l16  = lane & 15;
  const int wm = wv >> 1, wn = wv & 1;
  const int m0 = blockIdx.y * 128;
  const int wix = (NW == 1) ? 0 : (blockIdx.x >> 4);
  const int n0  = ((NW == 1) ? blockIdx.x : (blockIdx.x & 15)) * 128;

  const void* Wp = (wix == 0) ? W0 : (wix == 1) ? W1 : W2;
  const float* bias = (wix == 0) ? bias0 : (wix == 1) ? bias1 : bias2;
  void* Cp = (wix == 0) ? C0 : (wix == 1) ? C1 : C2;

  f32x4 acc[4][4];
#pragma unroll
  for (int i = 0; i < 4; i++)
#pragma unroll
    for (int j = 0; j < 4; j++) acc[i][j] = (f32x4)0.0f;

  const int g0 = tid, g1 = tid + 256;
  const int r0 = g0 >> 2, c0 = (g0 & 3) * 8;
  const int r1 = g1 >> 2, c1 = (g1 & 3) * 8;

  for (int k0 = 0; k0 < HIDDEN; k0 += 32) {
    __builtin_amdgcn_global_load_lds(
      (const __attribute__((address_space(1))) void*)(A + (size_t)(m0 + r0) * HIDDEN + k0 + c0),
      (__attribute__((address_space(3))) void*)(As + g0 * 8), 16, 0, 0);
    __builtin_amdgcn_global_load_lds(
      (const __attribute__((address_space(1))) void*)(A + (size_t)(m0 + r1) * HIDDEN + k0 + c1),
      (__attribute__((address_space(3))) void*)(As + g1 * 8), 16, 0, 0);
    if (W_BF16) {
      const u16* Wb = (const u16*)Wp;
      __builtin_amdgcn_global_load_lds(
        (const __attribute__((address_space(1))) void*)(Wb + (size_t)(n0 + r0) * HIDDEN + k0 + c0),
        (__attribute__((address_space(3))) void*)(Bs + g0 * 8), 16, 0, 0);
      __builtin_amdgcn_global_load_lds(
        (const __attribute__((address_space(1))) void*)(Wb + (size_t)(n0 + r1) * HIDDEN + k0 + c1),
        (__attribute__((address_space(3))) void*)(Bs + g1 * 8), 16, 0, 0);
    } else {
      const float* Wf = (const float*)Wp;
      const float* p0 = Wf + (size_t)(n0 + r0) * HIDDEN + k0 + c0;
      const float* p1 = Wf + (size_t)(n0 + r1) * HIDDEN + k0 + c1;
      f32x4 x0 = *(const f32x4*)p0, x1 = *(const f32x4*)(p0 + 4);
      f32x4 y0 = *(const f32x4*)p1, y1 = *(const f32x4*)(p1 + 4);
      frag8 b0v, b1v;
#pragma unroll
      for (int e = 0; e < 4; e++) {
        b0v[e]   = (short)f2bf(x0[e]); b0v[e+4] = (short)f2bf(x1[e]);
        b1v[e]   = (short)f2bf(y0[e]); b1v[e+4] = (short)f2bf(y1[e]);
      }
      *(frag8*)&Bs[g0 * 8] = b0v;
      *(frag8*)&Bs[g1 * 8] = b1v;
    }

    __builtin_amdgcn_s_waitcnt(0);   // drain DMA before barrier
    __syncthreads();

    frag8 af[4], bfr[4];
#pragma unroll
    for (int mt = 0; mt < 4; mt++)
      af[mt] = *(const frag8*)&As[(wm*64 + mt*16 + l16) * 32 + quad*8];
#pragma unroll
    for (int nt = 0; nt < 4; nt++)
      bfr[nt] = *(const frag8*)&Bs[(wn*64 + nt*16 + l16) * 32 + quad*8];
#pragma unroll
    for (int mt = 0; mt < 4; mt++)
#pragma unroll
      for (int nt = 0; nt < 4; nt++)
        acc[mt][nt] = __builtin_amdgcn_mfma_f32_16x16x32_bf16(af[mt], bfr[nt], acc[mt][nt], 0, 0, 0);

    __syncthreads();
  }

  if (VT && wix == 2) {
    u16* Cv = (u16*)Cp;
    u16* T = smem + wv * 1056;
#pragma unroll
    for (int nt = 0; nt < 4; nt++) {
      const int n  = n0 + wn*64 + nt*16 + l16;
      const float bv = bias[n];
#pragma unroll
      for (int mt = 0; mt < 4; mt++)
#pragma unroll
        for (int r = 0; r < 4; r++)
          T[l16 * 66 + mt*16 + quad*4 + r] = f2bf(acc[mt][nt][r] + bv);
#pragma unroll
      for (int rr = 0; rr < 16; rr++) {
        const int nn = n0 + wn*64 + nt*16 + rr;
        const int mm = m0 + wm*64 + lane;
        const int b = mm >> 11, s = mm & 2047;
        Cv[((size_t)(b * HIDDEN + nn)) * SEQ + s] = T[rr * 66 + lane];
      }
    }
  } else {
#pragma unroll
    for (int nt = 0; nt < 4; nt++) {
      const int n  = n0 + wn*64 + nt*16 + l16;
      const float bv = bias[n];
#pragma unroll
      for (int mt = 0; mt < 4; mt++) {
#pragma unroll
        for (int r = 0; r < 4; r++) {
          const int m = m0 + wm*64 + mt*16 + quad*4 + r;
          if (C_F32) ((float*)Cp)[(size_t)m * HIDDEN + n] = acc[mt][nt][r] + bv;
          else       ((u16*)Cp)[(size_t)m * HIDDEN + n]   = f2bf(acc[mt][nt][r] + bv);
        }
      }
    }
  }
}

// ---------------------------------------------------------------------------
// NEW: deep-pipelined QKV GEMM (T1+T2+T3+T4+T5).
// Tile 256(M) x 128(N), BK=64.  512 thr = 8 waves (2M x 4N); per-wave 128x32.
// 3 LDS buffers x (A[256][64] + B[128][64]) bf16 = 144 KiB; staged 2 K-tiles
// ahead with global_load_lds w=16; counted vmcnt(6) (never drained in loop).
// LDS XOR-swizzle: 16B slot ^= (row&7), applied as pre-swizzled GLOBAL source
// (linear LDS dest, rule #21) + swizzled ds_read -> 2-way (free) reads.
// Grid = 768 (48 colTiles x 16 rowTiles) = exactly 3 waves of 256 CUs.
// ---------------------------------------------------------------------------
#define NT32 32   // 2048 / 64 K-tiles

#define STG(gptr, lofs) __builtin_amdgcn_global_load_lds( \
    (const __attribute__((address_space(1))) void*)(gptr), \
    (__attribute__((address_space(3))) void*)(smem + (lofs)), 16, 0, 0)

// one K-tile group: 2 phases x {10 ds_read | 3 stage | bar | prio1 | 16 MFMA | prio0 | bar}
#define GRP(t, DOSTAGE, WAITSTR) { \
  u16* As = smem + ((t) % 3) * 24576; \
  u16* Bs = As + 16384; \
  frag8 af[8], bfr[2]; \
  _Pragma("unroll") for (int mt = 0; mt < 8; mt++) \
    af[mt] = *(const frag8*)(As + abase + mt*1024 + s0q); \
  bfr[0] = *(const frag8*)(Bs + bbase + s0q); \
  bfr[1] = *(const frag8*)(Bs + bbase + 1024 + s0q); \
  if (DOSTAGE) { \
    const size_t ko = (size_t)((t)+2)*64; const int sb = (((t)+2)%3)*24576; \
    STG(gA0 + ko, sb + ldsA0); STG(gA1 + ko, sb + ldsA1); STG(gB0 + ko, sb + ldsB0); \
  } \
  __builtin_amdgcn_s_barrier(); \
  __builtin_amdgcn_s_setprio(1); \
  _Pragma("unroll") for (int mt = 0; mt < 8; mt++) { \
    acc[mt][0] = __builtin_amdgcn_mfma_f32_16x16x32_bf16(af[mt], bfr[0], acc[mt][0], 0,0,0); \
    acc[mt][1] = __builtin_amdgcn_mfma_f32_16x16x32_bf16(af[mt], bfr[1], acc[mt][1], 0,0,0); \
  } \
  __builtin_amdgcn_s_setprio(0); \
  __builtin_amdgcn_s_barrier(); \
  _Pragma("unroll") for (int mt = 0; mt < 8; mt++) \
    af[mt] = *(const frag8*)(As + abase + mt*1024 + s1q); \
  bfr[0] = *(const frag8*)(Bs + bbase + s1q); \
  bfr[1] = *(const frag8*)(Bs + bbase + 1024 + s1q); \
  if (DOSTAGE) { \
    const size_t ko = (size_t)((t)+2)*64; const int sb = (((t)+2)%3)*24576; \
    STG(gA2 + ko, sb + ldsA2); STG(gA3 + ko, sb + ldsA3); STG(gB1 + ko, sb + ldsB1); \
  } \
  __builtin_amdgcn_s_barrier(); \
  __builtin_amdgcn_s_setprio(1); \
  _Pragma("unroll") for (int mt = 0; mt < 8; mt++) { \
    acc[mt][0] = __builtin_amdgcn_mfma_f32_16x16x32_bf16(af[mt], bfr[0], acc[mt][0], 0,0,0); \
    acc[mt][1] = __builtin_amdgcn_mfma_f32_16x16x32_bf16(af[mt], bfr[1], acc[mt][1], 0,0,0); \
  } \
  __builtin_amdgcn_s_setprio(0); \
  asm volatile("s_waitcnt " WAITSTR ::: "memory"); \
  __builtin_amdgcn_s_barrier(); \
}

__global__ __launch_bounds__(512, 2)
void gemm256_qkv(const u16* __restrict__ A,
                 const u16* __restrict__ W0, const u16* __restrict__ W1,
                 const u16* __restrict__ W2,
                 const float* __restrict__ bias0, const float* __restrict__ bias1,
                 const float* __restrict__ bias2,
                 u16* __restrict__ C0, u16* __restrict__ C1, u16* __restrict__ Vt)
{
  __shared__ __align__(16) u16 smem[73728];   // 144 KiB: 3 x (A 16384 + B 8192) u16

  const int tid  = threadIdx.x;
  const int lane = tid & 63;
  const int wv   = tid >> 6;            // 0..7
  const int quad = lane >> 4;
  const int l16  = lane & 15;
  const int wm = wv >> 2, wn = wv & 3;  // 2M x 4N wave layout

  // XCD-aware bijective swizzle (768 % 8 == 0): per-XCD chunk = 6 colTiles.
  const int bid = blockIdx.x;
  const int sbid = (bid & 7) * 96 + (bid >> 3);
  const int colTile = sbid >> 4;        // 0..47
  const int rowTile = sbid & 15;        // 0..15
  const int wix = colTile >> 4;         // 0:Q 1:K 2:V
  const int n0  = (colTile & 15) * 128; // col within weight
  const int m0  = rowTile * 256;

  const u16* Wp = (wix == 0) ? W0 : (wix == 1) ? W1 : W2;
  const float* bias = (wix == 0) ? bias0 : (wix == 1) ? bias1 : bias2;

  // --- staging constants.  Chunk = 1 KiB = 8 rows x 128B.  Lane l covers
  // row (l>>3), 16B slot (l&7); inverse-swizzled global granule:
  const int c8 = (lane & 7) ^ (lane >> 3);
  const int rA = lane >> 3;
  const u16* gA0 = A  + (size_t)(m0 + wv*32 +  0 + rA) * HIDDEN + c8*8;
  const u16* gA1 = A  + (size_t)(m0 + wv*32 +  8 + rA) * HIDDEN + c8*8;
  const u16* gA2 = A  + (size_t)(m0 + wv*32 + 16 + rA) * HIDDEN + c8*8;
  const u16* gA3 = A  + (size_t)(m0 + wv*32 + 24 + rA) * HIDDEN + c8*8;
  const u16* gB0 = Wp + (size_t)(n0 + wv*16 +  0 + rA) * HIDDEN + c8*8;
  const u16* gB1 = Wp + (size_t)(n0 + wv*16 +  8 + rA) * HIDDEN + c8*8;
  const int ldsA0 = (4*wv)*512 + lane*8;          // linear LDS dest (u16)
  const int ldsA1 = ldsA0 + 512;
  const int ldsA2 = ldsA0 + 1024;
  const int ldsA3 = ldsA0 + 1536;
  const int ldsB0 = 16384 + (2*wv)*512 + lane*8;
  const int ldsB1 = ldsB0 + 512;

  // --- fragment-read constants (swizzled): slot s ^= (row&7), row&7 == l16&7
  const int s0q = ((quad    ) ^ (l16 & 7)) * 8;   // ks=0 slots 0..3
  const int s1q = ((quad + 4) ^ (l16 & 7)) * 8;   // ks=1 slots 4..7
  const int abase = (wm*128 + l16) * 64;
  const int bbase = (wn*32  + l16) * 64;

  f32x4 acc[8][2];
#pragma unroll
  for (int i = 0; i < 8; i++) { acc[i][0] = (f32x4)0.0f; acc[i][1] = (f32x4)0.0f; }

  // --- prologue: stage tiles 0 and 1 (6 loads each), wait tile 0.
  STG(gA0, ldsA0); STG(gA1, ldsA1); STG(gB0, ldsB0);
  STG(gA2, ldsA2); STG(gA3, ldsA3); STG(gB1, ldsB1);
  STG(gA0 + 64, 24576 + ldsA0); STG(gA1 + 64, 24576 + ldsA1); STG(gB0 + 64, 24576 + ldsB0);
  STG(gA2 + 64, 24576 + ldsA2); STG(gA3 + 64, 24576 + ldsA3); STG(gB1 + 64, 24576 + ldsB1);
  asm volatile("s_waitcnt vmcnt(6)" ::: "memory");
  __builtin_amdgcn_s_barrier();

  // --- main pipeline: compute tile t, stage tile t+2; trailing vmcnt(6)
  for (int t = 0; t < NT32 - 2; ++t) GRP(t, 1, "vmcnt(6)");
  GRP(NT32 - 2, 0, "vmcnt(0)");     // single tail drain: tile NT-1 ready
  GRP(NT32 - 1, 0, "vmcnt(63)");    // no-op wait

  // --- epilogue.  C/D: col(n)=l16, row(m)=quad*4+r.
  if (wix != 2) {
    u16* Cb = (wix == 0) ? C0 : C1;
#pragma unroll
    for (int nt = 0; nt < 2; nt++) {
      const int n = n0 + wn*32 + nt*16 + l16;
      const float bv = bias[n];
#pragma unroll
      for (int mt = 0; mt < 8; mt++) {
        const int m = m0 + wm*128 + mt*16 + quad*4;
#pragma unroll
        for (int r = 0; r < 4; r++)
          Cb[(size_t)(m + r) * HIDDEN + n] = f2bf(acc[mt][nt][r] + bv);
      }
    }
  } else {
    // V: transposed store via per-wave LDS staging (smem reuse post-barrier).
    u16* T = smem + wv * 2176;         // 16 x 136 u16 per wave
    const int b  = m0 >> 11;
    const int s0 = (m0 & 2047) + wm*128;
#pragma unroll
    for (int nt = 0; nt < 2; nt++) {
      const int nloc = n0 + wn*32 + nt*16;
      const float bv = bias[nloc + l16];
#pragma unroll
      for (int mt = 0; mt < 8; mt++)
#pragma unroll
        for (int r = 0; r < 4; r++)
          T[l16*136 + mt*16 + quad*4 + r] = f2bf(acc[mt][nt][r] + bv);
#pragma unroll
      for (int rr = 0; rr < 16; rr++) {
        const size_t vb = ((size_t)(b * HIDDEN + nloc + rr)) * SEQ + s0;
        Vt[vb + lane]      = T[rr*136 + lane];
        Vt[vb + 64 + lane] = T[rr*136 + 64 + lane];
      }
    }
  }
}

// ---------------------------------------------------------------------------
// RoPE in place on bf16 Q,K; 8 d/thread.  Q pre-scaled by 1/sqrt(128).
// ---------------------------------------------------------------------------
__global__ void rope_kernel(u16* __restrict__ Q, u16* __restrict__ K)
{
  const int tid = blockIdx.x * 256 + threadIdx.x;   // 2^20 total
  const int t   = tid >> 19;           // 0:Q 1:K
  const int r   = tid & 524287;
  const int row = r >> 7;              // [0,4096)
  const int grp = r & 127;
  const int h   = grp >> 3, d0 = (grp & 7) * 8;
  u16* X = t ? K : Q;
  const float s = (float)(row & 2047);
  const float qscale = t ? 1.0f : 0.08838834764831845f;
  const size_t base = (size_t)row * HIDDEN + h * HDIM + d0;
  frag8 a = *(const frag8*)(X + base);
  frag8 b = *(const frag8*)(X + base + 64);
  frag8 oa, ob;
#pragma unroll
  for (int e = 0; e < 8; e++) {
    const float inv = __expf(-(float)(d0 + e) * (9.210340371976184f / 64.0f));
    float sn, c;
    __sincosf(s * inv, &sn, &c);
    const float x1 = bf2f((u16)a[e]), x2 = bf2f((u16)b[e]);
    oa[e] = (short)f2bf((x1 * c - x2 * sn) * qscale);
    ob[e] = (short)f2bf((x2 * c + x1 * sn) * qscale);
  }
  *(frag8*)(X + base)      = oa;
  *(frag8*)(X + base + 64) = ob;
}

// ---------------------------------------------------------------------------
// Flash attention (causal) — unchanged this round.
// ---------------------------------------------------------------------------
#define KS_STR 132
#define VS_STR 68
#define PS_STR 68
__global__ __launch_bounds__(256, 3)
void attn_kernel(const u16* Q, const u16* __restrict__ K,
                 const u16* __restrict__ Vt, u16* O)
{
  __shared__ __align__(16) u16 Ks[64 * KS_STR];
  __shared__ __align__(16) u16 Vs[128 * VS_STR];
  __shared__ __align__(16) u16 Ps[4 * 16 * PS_STR];

  const int bx = blockIdx.x;
  const int g  = bx >> 5;
  const int bh = bx & 31;
  const int qt = (g & 1) ? (31 - (g >> 1)) : (g >> 1);
  const int b = bh >> 4, h = bh & 15;

  const int tid = threadIdx.x, lane = tid & 63, wv = tid >> 6;
  const int quad = lane >> 4, l16 = lane & 15;

  frag8 qf[4];
  const size_t qbase = ((size_t)(b * SEQ) + qt*64 + wv*16) * HIDDEN + h * HDIM;
#pragma unroll
  for (int ks = 0; ks < 4; ks++)
    qf[ks] = *(const frag8*)(Q + qbase + (size_t)l16 * HIDDEN + ks*32 + quad*8);

  f32x4 Oacc[8];
#pragma unroll
  for (int dt = 0; dt < 8; dt++) Oacc[dt] = (f32x4)0.0f;
  float m_i[4], l_i[4];
#pragma unroll
  for (int r = 0; r < 4; r++) { m_i[r] = -1e30f; l_i[r] = 0.0f; }

  const int ktmax = qt + 1;
  const size_t krow0 = (size_t)(b * SEQ) * HIDDEN + h * HDIM;
  const size_t vrow0 = (size_t)(b * HIDDEN + h * HDIM) * SEQ;
  u16* Pw = Ps + wv * (16 * PS_STR);
  const int qmin = qt*64 + wv*16;

  for (int kt = 0; kt < ktmax; kt++) {
#pragma unroll
    for (int it = 0; it < 4; it++) {
      const int G = it * 256 + tid;
      const int key = G >> 4, gd = (G & 15) * 8;
      *(frag8*)&Ks[key * KS_STR + gd] =
        *(const frag8*)(K + krow0 + (size_t)(kt*64 + key) * HIDDEN + gd);
    }
#pragma unroll
    for (int it = 0; it < 4; it++) {
      const int G = it * 256 + tid;
      const int d = G >> 3, j8 = (G & 7) * 8;
      *(frag8*)&Vs[d * VS_STR + j8] =
        *(const frag8*)(Vt + vrow0 + (size_t)d * SEQ + kt*64 + j8);
    }
    __syncthreads();

    f32x4 st[4];
#pragma unroll
    for (int jt = 0; jt < 4; jt++) st[jt] = (f32x4)0.0f;

#pragma unroll
    for (int ks = 0; ks < 4; ks++) {
      frag8 kf[4];
#pragma unroll
      for (int jt = 0; jt < 4; jt++)
        kf[jt] = *(const frag8*)&Ks[(jt*16 + l16) * KS_STR + ks*32 + quad*8];
#pragma unroll
      for (int jt = 0; jt < 4; jt++)
        st[jt] = __builtin_amdgcn_mfma_f32_16x16x32_bf16(qf[ks], kf[jt], st[jt], 0, 0, 0);
    }

    if (kt == qt) {
#pragma unroll
      for (int jt = 0; jt < 4; jt++) {
        const int jl = jt*16 + l16;
#pragma unroll
        for (int r = 0; r < 4; r++) {
          const int ml = wv*16 + quad*4 + r;
          st[jt][r] = (jl <= ml) ? st[jt][r] : -1e30f;
        }
      }
    }

    float alpha[4];
#pragma unroll
    for (int r = 0; r < 4; r++) {
      float cm = st[0][r];
#pragma unroll
      for (int jt = 1; jt < 4; jt++) cm = fmaxf(cm, st[jt][r]);
      cm = fmaxf(cm, __shfl_xor(cm, 1, 64));
      cm = fmaxf(cm, __shfl_xor(cm, 2, 64));
      cm = fmaxf(cm, __shfl_xor(cm, 4, 64));
      cm = fmaxf(cm, __shfl_xor(cm, 8, 64));
      const float mnew = fmaxf(m_i[r], cm);
      alpha[r] = __expf(m_i[r] - mnew);
      m_i[r] = mnew;
    }

    float csum[4];
#pragma unroll
    for (int r = 0; r < 4; r++) csum[r] = 0.0f;
#pragma unroll
    for (int jt = 0; jt < 4; jt++)
#pragma unroll
      for (int r = 0; r < 4; r++) {
        const float p = __expf(st[jt][r] - m_i[r]);
        csum[r] += p;
        Pw[(quad*4 + r) * PS_STR + jt*16 + l16] = f2bf(p);
      }
#pragma unroll
    for (int r = 0; r < 4; r++) {
      float cs = csum[r];
      cs += __shfl_xor(cs, 1, 64);
      cs += __shfl_xor(cs, 2, 64);
      cs += __shfl_xor(cs, 4, 64);
      cs += __shfl_xor(cs, 8, 64);
      l_i[r] = l_i[r] * alpha[r] + cs;
#pragma unroll
      for (int dt = 0; dt < 8; dt++) Oacc[dt][r] *= alpha[r];
    }

#pragma unroll
    for (int ks2 = 0; ks2 < 2; ks2++) {
      frag8 pf = *(const frag8*)&Pw[l16 * PS_STR + ks2*32 + quad*8];
#pragma unroll
      for (int dt = 0; dt < 8; dt++) {
        frag8 vf = *(const frag8*)&Vs[(dt*16 + l16) * VS_STR + ks2*32 + quad*8];
        Oacc[dt] = __builtin_amdgcn_mfma_f32_16x16x32_bf16(pf, vf, Oacc[dt], 0, 0, 0);
      }
    }
    __syncthreads();
  }

#pragma unroll
  for (int r = 0; r < 4; r++) {
    const float inv = 1.0f / l_i[r];
    const int m = qmin + quad*4 + r;
#pragma unroll
    for (int dt = 0; dt < 8; dt++) {
      const int d = dt*16 + l16;
      O[((size_t)(b * SEQ) + m) * HIDDEN + h * HDIM + d] = f2bf(Oacc[dt][r] * inv);
    }
  }
}

// ---------------------------------------------------------------------------
extern "C" void kernel_launch(void* const* d_in, const int* in_sizes, int n_in,
                              void* d_out, int out_size, void* d_ws, size_t ws_size,
                              hipStream_t stream)
{
  const float* X  = (const float*)d_in[0];
  const float* Wq = (const float*)d_in[1];
  const float* bq = (const float*)d_in[2];
  const float* Wk = (const float*)d_in[3];
  const float* bk = (const float*)d_in[4];
  const float* Wv = (const float*)d_in[5];
  const float* bv = (const float*)d_in[6];
  const float* Wo = (const float*)d_in[7];
  const float* bo = (const float*)d_in[8];
  float* out = (float*)d_out;

  u16* Kb = (u16*)d_out;
  u16* Xb = (u16*)d_out + (8u << 20);
  char* ws = (char*)d_ws;
  u16* Qb  = (u16*)ws;
  u16* Vtb = (u16*)(ws + (16u << 20));

  dim3 blk(256);
  const bool fast = ws_size >= (64u << 20);
  if (fast) {
    u16* Wqb = (u16*)(ws + (32u << 20));
    u16* Wkb = (u16*)(ws + (40u << 20));
    u16* Wvb = (u16*)(ws + (48u << 20));
    u16* Wob = (u16*)(ws + (56u << 20));
    cvt_all<<<12288, blk, 0, stream>>>(X, Wq, Wk, Wv, Wo, Xb, Wqb, Wkb, Wvb, Wob);
    gemm256_qkv<<<dim3(768), dim3(512), 0, stream>>>(
        Xb, Wqb, Wkb, Wvb, bq, bk, bv, Qb, Kb, Vtb);
    rope_kernel<<<4096, blk, 0, stream>>>(Qb, Kb);
    attn_kernel<<<1024, blk, 0, stream>>>(Qb, Kb, Vtb, Qb);
    gemm_fused<1,1,0,1><<<dim3(16,32), blk, 0, stream>>>(
        Qb, Wob, Wob, Wob, bo, bo, bo, out, out, out);
  } else {
    cvt_all<<<4096, blk, 0, stream>>>(X, Wq, Wk, Wv, Wo, Xb, Xb, Xb, Xb, Xb);
    gemm_fused<0,3,1,0><<<dim3(48,32), blk, 0, stream>>>(
        Xb, Wq, Wk, Wv, bq, bk, bv, Qb, Kb, Vtb);
    rope_kernel<<<4096, blk, 0, stream>>>(Qb, Kb);
    attn_kernel<<<1024, blk, 0, stream>>>(Qb, Kb, Vtb, Qb);
    gemm_fused<0,1,0,1><<<dim3(16,32), blk, 0, stream>>>(
        Qb, Wo, Wo, Wo, bo, bo, bo, out, out, out);
  }
}